// Round 11
// baseline (466.788 us; speedup 1.0000x reference)
//
#include <hip/hip_runtime.h>

// PointEncoderV6 — MI355X fp32 implementation. Round 11.
// R11 change (single variable): attn 2 queries/thread (128 thr/block,
// grid (4,8,40)). Per LDS K/V row read -> 2 scores / 2 PV FMAs: halves
// LDS-reads per FLOP. R10 showed barriers/tile-size neutral; VALUBusy pinned
// ~56% => LDS-broadcast pipe balanced against VALU. Split-8, TILE=128 kept.

#define N_AG   6
#define N_ANCH 1024
#define C_FEAT 256
#define D_ANCH 8
#define KTOP   256
#define NM     1280          // (N-1)*K points per agent
#define NR     40960         // 5*8*1024 attention rows
#define ZROW   393216        // element offset of the zero row in mfeat (row 1536)
#define AC     262144        // N_ANCH * C_FEAT

__device__ __forceinline__ float waveSum(float v) {
  #pragma unroll
  for (int off = 32; off; off >>= 1) v += __shfl_down(v, off);
  return v;
}

// ---------------------------------------------------------------------------
// Kernel 1: fused cls MLP: roi = sigmoid(LN(relu(LN(relu(bf@w1+b1))@w2+b2))@w3+b3)
// 8 rows per block, 256 threads (thread = output column). Grid 768.
// ---------------------------------------------------------------------------
__global__ __launch_bounds__(256) void cls_kernel(
    const float* __restrict__ bf,
    const float* __restrict__ w1, const float* __restrict__ b1,
    const float* __restrict__ g1, const float* __restrict__ bb1,
    const float* __restrict__ w2, const float* __restrict__ b2,
    const float* __restrict__ g2, const float* __restrict__ bb2,
    const float* __restrict__ w3, const float* __restrict__ b3,
    float* __restrict__ roi)
{
  __shared__ float xin[8][256];
  __shared__ float xout[8][256];
  __shared__ float stats[8][2];
  const int t = threadIdx.x;
  const int wid = t >> 6, lane = t & 63;
  const int r0 = blockIdx.x * 8;

  for (int r = 0; r < 8; ++r) xin[r][t] = bf[(r0 + r) * 256 + t];

  const float G1 = g1[t], B1 = bb1[t], G2 = g2[t], B2 = bb2[t];
  float acc[8];

  // ---- layer 1 GEMV ----
  #pragma unroll
  for (int r = 0; r < 8; ++r) acc[r] = b1[t];
  __syncthreads();
  for (int kk = 0; kk < 256; kk += 4) {
    const float wa = w1[(kk+0)*256+t], wb = w1[(kk+1)*256+t];
    const float wc = w1[(kk+2)*256+t], wd = w1[(kk+3)*256+t];
    #pragma unroll
    for (int r = 0; r < 8; ++r) {
      const float4 xv = *(const float4*)&xin[r][kk];
      acc[r] = fmaf(xv.x, wa, fmaf(xv.y, wb, fmaf(xv.z, wc, fmaf(xv.w, wd, acc[r]))));
    }
  }
  #pragma unroll
  for (int r = 0; r < 8; ++r) xout[r][t] = fmaxf(acc[r], 0.f);
  __syncthreads();
  // ---- LN 1 ----
  for (int r = wid; r < 8; r += 4) {
    float s = xout[r][lane] + xout[r][lane+64] + xout[r][lane+128] + xout[r][lane+192];
    s = waveSum(s);
    if (lane == 0) stats[r][0] = s * (1.f/256.f);
  }
  __syncthreads();
  for (int r = wid; r < 8; r += 4) {
    const float m = stats[r][0];
    const float d0 = xout[r][lane]-m, d1 = xout[r][lane+64]-m;
    const float d2 = xout[r][lane+128]-m, d3 = xout[r][lane+192]-m;
    const float s = waveSum(d0*d0 + d1*d1 + d2*d2 + d3*d3);
    if (lane == 0) stats[r][1] = 1.f / sqrtf(s * (1.f/256.f) + 1e-5f);
  }
  __syncthreads();
  #pragma unroll
  for (int r = 0; r < 8; ++r)
    xin[r][t] = (xout[r][t] - stats[r][0]) * stats[r][1] * G1 + B1;
  __syncthreads();

  // ---- layer 2 GEMV ----
  #pragma unroll
  for (int r = 0; r < 8; ++r) acc[r] = b2[t];
  for (int kk = 0; kk < 256; kk += 4) {
    const float wa = w2[(kk+0)*256+t], wb = w2[(kk+1)*256+t];
    const float wc = w2[(kk+2)*256+t], wd = w2[(kk+3)*256+t];
    #pragma unroll
    for (int r = 0; r < 8; ++r) {
      const float4 xv = *(const float4*)&xin[r][kk];
      acc[r] = fmaf(xv.x, wa, fmaf(xv.y, wb, fmaf(xv.z, wc, fmaf(xv.w, wd, acc[r]))));
    }
  }
  __syncthreads();
  #pragma unroll
  for (int r = 0; r < 8; ++r) xout[r][t] = fmaxf(acc[r], 0.f);
  __syncthreads();
  // ---- LN 2 ----
  for (int r = wid; r < 8; r += 4) {
    float s = xout[r][lane] + xout[r][lane+64] + xout[r][lane+128] + xout[r][lane+192];
    s = waveSum(s);
    if (lane == 0) stats[r][0] = s * (1.f/256.f);
  }
  __syncthreads();
  for (int r = wid; r < 8; r += 4) {
    const float m = stats[r][0];
    const float d0 = xout[r][lane]-m, d1 = xout[r][lane+64]-m;
    const float d2 = xout[r][lane+128]-m, d3 = xout[r][lane+192]-m;
    const float s = waveSum(d0*d0 + d1*d1 + d2*d2 + d3*d3);
    if (lane == 0) stats[r][1] = 1.f / sqrtf(s * (1.f/256.f) + 1e-5f);
  }
  __syncthreads();
  // ---- layer 3: dot with w3, sigmoid ----
  const float w3t = w3[t], b30 = b3[0];
  #pragma unroll
  for (int r = 0; r < 8; ++r) {
    const float xn = (xout[r][t] - stats[r][0]) * stats[r][1] * G2 + B2;
    xin[r][t] = xn * w3t;
  }
  __syncthreads();
  for (int r = wid; r < 8; r += 4) {
    float s = xin[r][lane] + xin[r][lane+64] + xin[r][lane+128] + xin[r][lane+192];
    s = waveSum(s);
    if (lane == 0) roi[r0 + r] = 1.f / (1.f + expf(-(s + b30)));
  }
}

// ---------------------------------------------------------------------------
// Kernel 2: exact top-256 of 1024 per agent via bitonic sort.
// ---------------------------------------------------------------------------
__global__ __launch_bounds__(512) void topk_kernel(
    const float* __restrict__ roi, int* __restrict__ top_idx, float* __restrict__ conf)
{
  __shared__ unsigned long long keys[1024];
  const int t = threadIdx.x;
  const int ag = blockIdx.x;
  for (int i = t; i < 1024; i += 512) {
    const unsigned int bits = __float_as_uint(roi[ag * 1024 + i]);
    keys[i] = ((unsigned long long)bits << 10) | (unsigned long long)(1023 - i);
  }
  __syncthreads();
  for (int k = 2; k <= 1024; k <<= 1) {
    for (int j = k >> 1; j > 0; j >>= 1) {
      const int i = ((t & ~(j - 1)) << 1) | (t & (j - 1));
      const int p = i | j;
      const unsigned long long a = keys[i], b = keys[p];
      const bool up = ((i & k) == 0);          // descending overall
      if ((a < b) == up) { keys[i] = b; keys[p] = a; }
      __syncthreads();
    }
  }
  if (t < 256) {
    const unsigned long long key = keys[t];
    const int idx = 1023 - (int)(key & 1023ull);
    const float sc = __uint_as_float((unsigned int)(key >> 10));
    top_idx[ag * 256 + t] = idx;
    conf[ag * 256 + t] = (sc > 0.7f) ? 1.0f : 0.0f;
  }
}

// ---------------------------------------------------------------------------
// Kernel 3 (fused): blocks [0,1536]: mfeat gather (+zero row at 1536);
// blocks [1537,1782]: prep (b_anchor passthrough, boxes, pts SoA gather).
// ---------------------------------------------------------------------------
__global__ __launch_bounds__(256) void gather_prep_kernel(
    const float* __restrict__ bf, const int* __restrict__ top_idx,
    const float* __restrict__ conf, const float* __restrict__ ba,
    const float* __restrict__ i2j,
    float* __restrict__ mfeat, float* __restrict__ out,
    float* __restrict__ minmax, float* __restrict__ pts)
{
  const int t = threadIdx.x;
  const int blk = blockIdx.x;
  if (blk < 1536) {
    const int j = blk >> 8, idx = top_idx[blk];
    const float c = conf[blk];
    mfeat[blk * 256 + t] = bf[(j * 1024 + idx) * 256 + t] * c;
    return;
  }
  if (blk == 1536) { mfeat[ZROW + t] = 0.f; return; }
  const int id = (blk - 1537) * 256 + t;
  if (id < 49152) {                       // b_anchor passthrough (6*1024*8)
    out[id] = ba[id];
  } else if (id < 49152 + 6144) {         // boxes
    const int i = id - 49152;
    const float* p = ba + i * 8;
    const float cx = p[0], cy = p[1], cz = p[2];
    const float d0 = expf(p[3]), d1 = expf(p[4]), d2 = expf(p[5]);
    const float s = fabsf(p[6]), c = fabsf(p[7]);
    const float hx = 0.5f * (d0 * c + d1 * s);
    const float hy = 0.5f * (d0 * s + d1 * c);
    const float hz = 0.5f * d2;
    float* mm = minmax + i * 6;
    mm[0] = cx - hx; mm[1] = cy - hy; mm[2] = cz - hz;
    mm[3] = cx + hx; mm[4] = cy + hy; mm[5] = cz + hz;
  } else if (id < 49152 + 6144 + 7680) {  // pts (SoA)
    const int i = id - 55296;
    const int n = i / NM, jk = i % NM;
    const int jj = jk >> 8, k = jk & 255;
    const int j = jj + (jj >= n ? 1 : 0);
    const int idx = top_idx[j * 256 + k];
    const float* src = i2j + (((long)(n * 6 + j)) * 1024 + idx) * 8;
    float* dst = pts + n * 3840;
    dst[jk]        = src[0];
    dst[1280 + jk] = src[1];
    dst[2560 + jk] = src[2];
  }
}

// ---------------------------------------------------------------------------
// Kernel 5 (fused QKV): blocks [0,127]: Q=(ego+pos)@wq+bq (1024 rows);
// [128,767]: K=neigh@wk+bk (5120 rows); [768,1407]: V=neigh@wv+bv.
// ---------------------------------------------------------------------------
__global__ __launch_bounds__(256) void qkv_kernel(
    const float* __restrict__ bf, const float* __restrict__ ae,
    const float* __restrict__ wq, const float* __restrict__ bq,
    const float* __restrict__ wk, const float* __restrict__ bk,
    const float* __restrict__ wv, const float* __restrict__ bv,
    float* __restrict__ qb, float* __restrict__ kb, float* __restrict__ vb)
{
  __shared__ float xin[8][256];
  const int t = threadIdx.x;
  const int blk = blockIdx.x;
  const float* in; const float* add = nullptr;
  const float* w; const float* bias; float* outp; long r0;
  if (blk < 128)      { in = bf;      add = ae; w = wq; bias = bq; outp = qb; r0 = (long)blk * 8; }
  else if (blk < 768) { in = bf + AC;           w = wk; bias = bk; outp = kb; r0 = (long)(blk - 128) * 8; }
  else                { in = bf + AC;           w = wv; bias = bv; outp = vb; r0 = (long)(blk - 768) * 8; }

  for (int r = 0; r < 8; ++r) {
    float v = in[(r0 + r) * 256 + t];
    if (add) v += add[(r0 + r) * 256 + t];
    xin[r][t] = v;
  }
  __syncthreads();
  float acc[8];
  #pragma unroll
  for (int r = 0; r < 8; ++r) acc[r] = bias[t];
  for (int kk = 0; kk < 256; kk += 4) {
    const float wa = w[(kk+0)*256+t], wb = w[(kk+1)*256+t];
    const float wc = w[(kk+2)*256+t], wd = w[(kk+3)*256+t];
    #pragma unroll
    for (int r = 0; r < 8; ++r) {
      const float4 xv = *(const float4*)&xin[r][kk];
      acc[r] = fmaf(xv.x, wa, fmaf(xv.y, wb, fmaf(xv.z, wc, fmaf(xv.w, wd, acc[r]))));
    }
  }
  for (int r = 0; r < 8; ++r) outp[(r0 + r) * 256 + t] = acc[r];
}

// ---------------------------------------------------------------------------
// Kernel 6: flash attention, key-split x SPLITS, K-tile = 128 keys (32KB LDS).
// Grid (4, 8, 5*SPLITS), 128 threads (2 waves). THREAD = TWO QUERIES
// (q0 = bx*256+t and q0+128): each LDS K/V row read feeds 2 score/PV chains
// (halves LDS reads per FLOP; ILP-2 on the FMA chains).
// 8-key register mini-chunks: <=1 rescale per 8 keys per query.
// ---------------------------------------------------------------------------
template<int SPLITS>
__global__ __launch_bounds__(128) void attn_kernel(
    const float* __restrict__ q, const float* __restrict__ kb,
    const float* __restrict__ vb, float* __restrict__ po,
    float* __restrict__ pml, float* __restrict__ ob)
{
  __shared__ float ks[128][32];
  __shared__ float vs[128][32];
  const int t = threadIdx.x;             // 0..127
  const int h = blockIdx.y;
  const int b = blockIdx.z / SPLITS;
  const int split = blockIdx.z % SPLITS;
  const int q0 = blockIdx.x * 256 + t;   // this thread: queries q0, q0+128
  const int hh = h * 32;
  const float SCALE = 0.17677669529663687f;   // 1/sqrt(32)
  float qv0[32], qv1[32];
  #pragma unroll
  for (int d0 = 0; d0 < 32; d0 += 4) {
    const float4 v0 = *(const float4*)&q[q0 * 256 + hh + d0];
    qv0[d0] = v0.x * SCALE; qv0[d0+1] = v0.y * SCALE;
    qv0[d0+2] = v0.z * SCALE; qv0[d0+3] = v0.w * SCALE;
    const float4 v1 = *(const float4*)&q[(q0 + 128) * 256 + hh + d0];
    qv1[d0] = v1.x * SCALE; qv1[d0+1] = v1.y * SCALE;
    qv1[d0+2] = v1.z * SCALE; qv1[d0+3] = v1.w * SCALE;
  }
  float m0 = -1e30f, l0 = 0.f, m1 = -1e30f, l1 = 0.f;
  float o0[32], o1[32];
  #pragma unroll
  for (int d = 0; d < 32; ++d) { o0[d] = 0.f; o1[d] = 0.f; }
  const float* kbase = kb + (long)b * 1024 * 256;
  const float* vbase = vb + (long)b * 1024 * 256;
  const int KEYS = 1024 / SPLITS;
  const int k0 = split * KEYS;
  for (int c0 = k0; c0 < k0 + KEYS; c0 += 128) {   // 1 tile at SPLITS=8
    __syncthreads();
    for (int i = t; i < 1024; i += 128) {          // 128x32 K, float4
      const int kk = i >> 3, d = (i & 7) << 2;
      *(float4*)&ks[kk][d] = *(const float4*)&kbase[(c0 + kk) * 256 + hh + d];
    }
    for (int i = t; i < 1024; i += 128) {          // 128x32 V, float4
      const int kk = i >> 3, d = (i & 7) << 2;
      *(float4*)&vs[kk][d] = *(const float4*)&vbase[(c0 + kk) * 256 + hh + d];
    }
    __syncthreads();
    #pragma unroll 1
    for (int kk0 = 0; kk0 < 128; kk0 += 8) {
      float s0[8], s1[8];
      #pragma unroll
      for (int u = 0; u < 8; ++u) {
        const float* krow = &ks[kk0 + u][0];
        float a0 = 0.f, a1 = 0.f;
        #pragma unroll
        for (int d = 0; d < 32; ++d) {
          const float kd = krow[d];
          a0 = fmaf(qv0[d], kd, a0);
          a1 = fmaf(qv1[d], kd, a1);
        }
        s0[u] = a0; s1[u] = a1;
      }
      float c0m = s0[0], c1m = s1[0];
      #pragma unroll
      for (int u = 1; u < 8; ++u) { c0m = fmaxf(c0m, s0[u]); c1m = fmaxf(c1m, s1[u]); }
      if (c0m > m0) {
        const float sc = __expf(m0 - c0m);
        l0 *= sc;
        #pragma unroll
        for (int d = 0; d < 32; ++d) o0[d] *= sc;
        m0 = c0m;
      }
      if (c1m > m1) {
        const float sc = __expf(m1 - c1m);
        l1 *= sc;
        #pragma unroll
        for (int d = 0; d < 32; ++d) o1[d] *= sc;
        m1 = c1m;
      }
      #pragma unroll
      for (int u = 0; u < 8; ++u) {
        const float p0 = __expf(s0[u] - m0);
        const float p1 = __expf(s1[u] - m1);
        l0 += p0; l1 += p1;
        const float* vrow = &vs[kk0 + u][0];
        #pragma unroll
        for (int d = 0; d < 32; ++d) {
          const float vd = vrow[d];
          o0[d] = fmaf(p0, vd, o0[d]);
          o1[d] = fmaf(p1, vd, o1[d]);
        }
      }
    }
  }
  if (SPLITS == 1) {
    const float i0 = 1.f / l0, i1 = 1.f / l1;
    float* d0p = ob + ((long)b * 1024 + q0) * 256 + hh;
    float* d1p = ob + ((long)b * 1024 + q0 + 128) * 256 + hh;
    #pragma unroll
    for (int d = 0; d < 32; d += 4) {
      float4 v;
      v.x = o0[d]*i0; v.y = o0[d+1]*i0; v.z = o0[d+2]*i0; v.w = o0[d+3]*i0;
      *(float4*)&d0p[d] = v;
      v.x = o1[d]*i1; v.y = o1[d+1]*i1; v.z = o1[d+2]*i1; v.w = o1[d+3]*i1;
      *(float4*)&d1p[d] = v;
    }
  } else {
    const int R0 = (b * 8 + h) * 1024 + q0;
    float* p0d = po + ((long)split * NR + R0) * 32;
    float* p1d = po + ((long)split * NR + R0 + 128) * 32;
    #pragma unroll
    for (int d = 0; d < 32; d += 4) {
      float4 v;
      v.x = o0[d]; v.y = o0[d+1]; v.z = o0[d+2]; v.w = o0[d+3];
      *(float4*)&p0d[d] = v;
      v.x = o1[d]; v.y = o1[d+1]; v.z = o1[d+2]; v.w = o1[d+3];
      *(float4*)&p1d[d] = v;
    }
    float* pm0 = pml + ((long)split * NR + R0) * 2;
    pm0[0] = m0; pm0[1] = l0;
    float* pm1 = pml + ((long)split * NR + R0 + 128) * 2;
    pm1[0] = m1; pm1[1] = l1;
  }
}

// ---------------------------------------------------------------------------
// Kernel 6b: combine SPLITS partials -> normalized attention output.
// ---------------------------------------------------------------------------
template<int SPLITS>
__global__ __launch_bounds__(256) void attn_combine_kernel(
    const float* __restrict__ po, const float* __restrict__ pml,
    float* __restrict__ ob)
{
  const int id = blockIdx.x * 256 + threadIdx.x;
  const int R = id >> 5, d = id & 31;
  float M = -1e30f;
  #pragma unroll
  for (int s = 0; s < SPLITS; ++s)
    M = fmaxf(M, pml[((long)s * NR + R) * 2]);
  float L = 0.f, O = 0.f;
  #pragma unroll
  for (int s = 0; s < SPLITS; ++s) {
    const float w = __expf(pml[((long)s * NR + R) * 2] - M);
    L += pml[((long)s * NR + R) * 2 + 1] * w;
    O += po[((long)s * NR + R) * 32 + d] * w;
  }
  const int b = R >> 13, h = (R >> 10) & 7, qq = R & 1023;
  ob[((long)(b * 1024 + qq)) * 256 + h * 32 + d] = O / L;
}

// ---------------------------------------------------------------------------
// Kernel 7: res = 5*ego + (sum_b o_b) @ wo + 5*bo   (4 rows/block, grid 256)
// ---------------------------------------------------------------------------
__global__ __launch_bounds__(256) void res_kernel(
    const float* __restrict__ obuf, const float* __restrict__ bf,
    const float* __restrict__ wo, const float* __restrict__ bo,
    float* __restrict__ res)
{
  __shared__ float xin[4][256];
  const int t = threadIdx.x;
  const int r0 = blockIdx.x * 4;
  for (int r = 0; r < 4; ++r) {
    const long a = r0 + r;
    float v = 0.f;
    #pragma unroll
    for (int b = 0; b < 5; ++b) v += obuf[(b * 1024 + a) * 256 + t];
    xin[r][t] = v;
  }
  __syncthreads();
  float acc[4];
  #pragma unroll
  for (int r = 0; r < 4; ++r) acc[r] = 0.f;
  for (int kk = 0; kk < 256; kk += 4) {
    const float wa = wo[(kk+0)*256+t], wb = wo[(kk+1)*256+t];
    const float wc = wo[(kk+2)*256+t], wd = wo[(kk+3)*256+t];
    #pragma unroll
    for (int r = 0; r < 4; ++r) {
      const float4 xv = *(const float4*)&xin[r][kk];
      acc[r] = fmaf(xv.x, wa, fmaf(xv.y, wb, fmaf(xv.z, wc, fmaf(xv.w, wd, acc[r]))));
    }
  }
  const float bot = 5.f * bo[t];
  for (int r = 0; r < 4; ++r)
    res[(r0 + r) * 256 + t] = acc[r] + bot + 5.f * bf[(r0 + r) * 256 + t];
}

// ---------------------------------------------------------------------------
// Kernel 8: sparse box aggregation + final output. ONE anchor per block,
// grid 6144. Per-wave private compaction; conf-filtered list; ILP-4 gather.
// ---------------------------------------------------------------------------
__global__ __launch_bounds__(256) void agg_kernel(
    const float* __restrict__ pts, const float* __restrict__ minmax,
    const float* __restrict__ conf, const float* __restrict__ mfeat,
    const float* __restrict__ res, float* __restrict__ outf)
{
  __shared__ int list[NM];
  __shared__ int wcnt[4];      // padded list length per wave
  __shared__ int wicnt[4];     // inside count per wave
  const int t = threadIdx.x, w = t >> 6, lane = t & 63;
  const int n = blockIdx.x >> 10;
  const int a = blockIdx.x & 1023;

  const float* mm = minmax + (n * 1024 + a) * 6;
  const float mnx = mm[0], mny = mm[1], mnz = mm[2];
  const float mxx = mm[3], mxy = mm[4], mxz = mm[5];

  const float* P = pts + n * 3840;
  int localBase = 0, insideCnt = 0;
  #pragma unroll
  for (int s = 0; s < 5; ++s) {
    const int mpt = w * 320 + s * 64 + lane;
    const float x = P[mpt], y = P[1280 + mpt], z = P[2560 + mpt];
    const bool in = (x >= mnx) & (x <= mxx) & (y >= mny) & (y <= mxy) &
                    (z >= mnz) & (z <= mxz);
    const int jj = mpt >> 8;
    const int j = jj + (jj >= n ? 1 : 0);
    const int row = (j << 8) | (mpt & 255);
    const bool keep = in && (conf[row] > 0.f);
    const unsigned long long kmask = __ballot(keep);
    if (keep)
      list[w * 320 + localBase + __popcll(kmask & ((1ull << lane) - 1ull))] = row << 8;
    localBase += __popcll(kmask);
    insideCnt += __popcll(__ballot(in));
  }
  const int nwp = (localBase + 3) & ~3;
  if (lane < nwp - localBase) list[w * 320 + localBase + lane] = ZROW;
  if (lane == 0) { wcnt[w] = nwp; wicnt[w] = insideCnt; }
  __syncthreads();

  const int cnt = wicnt[0] + wicnt[1] + wicnt[2] + wicnt[3];
  float a0 = 0.f, a1 = 0.f, a2 = 0.f, a3 = 0.f;
  const float* mf = mfeat + t;
  #pragma unroll 1
  for (int ww = 0; ww < 4; ++ww) {
    const int base = ww * 320, nw = wcnt[ww];
    #pragma unroll 1
    for (int l = 0; l < nw; l += 4) {
      const int o0 = list[base + l],     o1 = list[base + l + 1];
      const int o2 = list[base + l + 2], o3 = list[base + l + 3];
      a0 += mf[o0]; a1 += mf[o1];     // offsets stored as element offsets (row*256)
      a2 += mf[o2]; a3 += mf[o3];
    }
  }
  const float acc = (a0 + a1) + (a2 + a3);
  outf[((long)(n * 1024 + a)) * 256 + t] =
      res[a * 256 + t] + acc / (float)(cnt > 0 ? cnt : 1);
}

// ---------------------------------------------------------------------------
extern "C" void kernel_launch(void* const* d_in, const int* in_sizes, int n_in,
                              void* d_out, int out_size, void* d_ws, size_t ws_size,
                              hipStream_t stream)
{
  (void)in_sizes; (void)n_in; (void)out_size;
  const float* i2j_anchor  = (const float*)d_in[0];
  const float* b_anchor    = (const float*)d_in[1];
  const float* b_feature   = (const float*)d_in[2];
  const float* anchor_embed= (const float*)d_in[5];
  const float* cls_w1 = (const float*)d_in[6];
  const float* cls_b1 = (const float*)d_in[7];
  const float* cls_g1 = (const float*)d_in[8];
  const float* cls_bb1= (const float*)d_in[9];
  const float* cls_w2 = (const float*)d_in[10];
  const float* cls_b2 = (const float*)d_in[11];
  const float* cls_g2 = (const float*)d_in[12];
  const float* cls_bb2= (const float*)d_in[13];
  const float* cls_w3 = (const float*)d_in[14];
  const float* cls_b3 = (const float*)d_in[15];
  const float* wq = (const float*)d_in[26];
  const float* bq = (const float*)d_in[27];
  const float* wk = (const float*)d_in[28];
  const float* bk = (const float*)d_in[29];
  const float* wv = (const float*)d_in[30];
  const float* bv = (const float*)d_in[31];
  const float* wo = (const float*)d_in[32];
  const float* bo = (const float*)d_in[33];
  float* out = (float*)d_out;

  // workspace layout (float offsets)
  float* ws = (float*)d_ws;
  float* roi    = ws;                 // 6144
  int*   tidx   = (int*)(ws + 6144);  // 1536
  float* conf   = ws + 7680;          // 1536
  float* mfeat  = ws + 9216;          // 393472 (1537 rows incl. zero row)
  float* qbuf   = ws + 402688;        // 262144
  float* kbuf   = ws + 664832;        // 1310720
  float* vbuf   = ws + 1975552;       // 1310720
  float* obuf   = ws + 3286272;       // 1310720
  float* resbuf = ws + 4596992;       // 262144
  float* minmax = ws + 4859136;       // 36864
  float* pts    = ws + 4896000;       // 23040 -> 4919040
  // split-8 layout:
  float* pml8 = ws + 4919040;         // 8*NR*2  = 655360
  float* po8  = ws + 5574400;         // 8*NR*32 = 10485760 -> 16060160
  // split-4 layout (compact):
  float* pml4 = ws + 4919040;         // 4*NR*2  = 327680
  float* po4  = ws + 5246720;         // 4*NR*32 = 5242880 -> 10489600
  const size_t need8  = (size_t)16060160 * sizeof(float);
  const size_t need4  = (size_t)10489600 * sizeof(float);

  cls_kernel<<<768, 256, 0, stream>>>(b_feature, cls_w1, cls_b1, cls_g1, cls_bb1,
                                      cls_w2, cls_b2, cls_g2, cls_bb2,
                                      cls_w3, cls_b3, roi);
  topk_kernel<<<6, 512, 0, stream>>>(roi, tidx, conf);
  gather_prep_kernel<<<1783, 256, 0, stream>>>(b_feature, tidx, conf, b_anchor,
                                               i2j_anchor, mfeat, out, minmax, pts);
  qkv_kernel<<<1408, 256, 0, stream>>>(b_feature, anchor_embed,
                                       wq, bq, wk, bk, wv, bv, qbuf, kbuf, vbuf);
  if (ws_size >= need8) {
    attn_kernel<8><<<dim3(4, 8, 40), 128, 0, stream>>>(qbuf, kbuf, vbuf, po8, pml8, nullptr);
    attn_combine_kernel<8><<<NR * 32 / 256, 256, 0, stream>>>(po8, pml8, obuf);
  } else if (ws_size >= need4) {
    attn_kernel<4><<<dim3(4, 8, 20), 128, 0, stream>>>(qbuf, kbuf, vbuf, po4, pml4, nullptr);
    attn_combine_kernel<4><<<NR * 32 / 256, 256, 0, stream>>>(po4, pml4, obuf);
  } else {
    attn_kernel<1><<<dim3(4, 8, 5), 128, 0, stream>>>(qbuf, kbuf, vbuf, nullptr, nullptr, obuf);
  }
  res_kernel<<<256, 256, 0, stream>>>(obuf, b_feature, wo, bo, resbuf);
  agg_kernel<<<6144, 256, 0, stream>>>(pts, minmax, conf, mfeat, resbuf, out + 49152);
}

// Round 12
// 336.357 us; speedup vs baseline: 1.3878x; 1.3878x over previous
//
#include <hip/hip_runtime.h>

// PointEncoderV6 — MI355X implementation. Round 12.
// R12: attention rewritten with MFMA 16x16x32 bf16 (d=32 = one MFMA K).
// Vector path plateaued at 114us (VALUBusy ~56%, R7/R10; R11 2q/thread
// regressed: VGPR 208 -> 9.5% occ). qkv now emits bf16 Q(pre-scaled)/K and
// transposed Vt[d][k]; no k-split -> combine kernel removed.
// C/D layout (m89-verified): col=lane&15, row=(lane>>4)*4+reg.
// A/B layout: row/col=lane%16, k-elems=8*(lane>>4)+j (CDNA doubled-K).

#define N_AG   6
#define N_ANCH 1024
#define C_FEAT 256
#define D_ANCH 8
#define KTOP   256
#define NM     1280          // (N-1)*K points per agent
#define ZROW   393216        // element offset of the zero row in mfeat (row 1536)
#define AC     262144        // N_ANCH * C_FEAT

using short8 = __attribute__((ext_vector_type(8))) short;
using f32x4  = __attribute__((ext_vector_type(4))) float;

__device__ __forceinline__ float waveSum(float v) {
  #pragma unroll
  for (int off = 32; off; off >>= 1) v += __shfl_down(v, off);
  return v;
}

__device__ __forceinline__ unsigned short f2bf(float x) {   // round-to-nearest-even
  const unsigned int b = __float_as_uint(x);
  return (unsigned short)((b + 0x7FFFu + ((b >> 16) & 1u)) >> 16);
}

// ---------------------------------------------------------------------------
// Kernel 1: fused cls MLP (unchanged from R10)
// ---------------------------------------------------------------------------
__global__ __launch_bounds__(256) void cls_kernel(
    const float* __restrict__ bf,
    const float* __restrict__ w1, const float* __restrict__ b1,
    const float* __restrict__ g1, const float* __restrict__ bb1,
    const float* __restrict__ w2, const float* __restrict__ b2,
    const float* __restrict__ g2, const float* __restrict__ bb2,
    const float* __restrict__ w3, const float* __restrict__ b3,
    float* __restrict__ roi)
{
  __shared__ float xin[8][256];
  __shared__ float xout[8][256];
  __shared__ float stats[8][2];
  const int t = threadIdx.x;
  const int wid = t >> 6, lane = t & 63;
  const int r0 = blockIdx.x * 8;

  for (int r = 0; r < 8; ++r) xin[r][t] = bf[(r0 + r) * 256 + t];

  const float G1 = g1[t], B1 = bb1[t], G2 = g2[t], B2 = bb2[t];
  float acc[8];

  #pragma unroll
  for (int r = 0; r < 8; ++r) acc[r] = b1[t];
  __syncthreads();
  for (int kk = 0; kk < 256; kk += 4) {
    const float wa = w1[(kk+0)*256+t], wb = w1[(kk+1)*256+t];
    const float wc = w1[(kk+2)*256+t], wd = w1[(kk+3)*256+t];
    #pragma unroll
    for (int r = 0; r < 8; ++r) {
      const float4 xv = *(const float4*)&xin[r][kk];
      acc[r] = fmaf(xv.x, wa, fmaf(xv.y, wb, fmaf(xv.z, wc, fmaf(xv.w, wd, acc[r]))));
    }
  }
  #pragma unroll
  for (int r = 0; r < 8; ++r) xout[r][t] = fmaxf(acc[r], 0.f);
  __syncthreads();
  for (int r = wid; r < 8; r += 4) {
    float s = xout[r][lane] + xout[r][lane+64] + xout[r][lane+128] + xout[r][lane+192];
    s = waveSum(s);
    if (lane == 0) stats[r][0] = s * (1.f/256.f);
  }
  __syncthreads();
  for (int r = wid; r < 8; r += 4) {
    const float m = stats[r][0];
    const float d0 = xout[r][lane]-m, d1 = xout[r][lane+64]-m;
    const float d2 = xout[r][lane+128]-m, d3 = xout[r][lane+192]-m;
    const float s = waveSum(d0*d0 + d1*d1 + d2*d2 + d3*d3);
    if (lane == 0) stats[r][1] = 1.f / sqrtf(s * (1.f/256.f) + 1e-5f);
  }
  __syncthreads();
  #pragma unroll
  for (int r = 0; r < 8; ++r)
    xin[r][t] = (xout[r][t] - stats[r][0]) * stats[r][1] * G1 + B1;
  __syncthreads();

  #pragma unroll
  for (int r = 0; r < 8; ++r) acc[r] = b2[t];
  for (int kk = 0; kk < 256; kk += 4) {
    const float wa = w2[(kk+0)*256+t], wb = w2[(kk+1)*256+t];
    const float wc = w2[(kk+2)*256+t], wd = w2[(kk+3)*256+t];
    #pragma unroll
    for (int r = 0; r < 8; ++r) {
      const float4 xv = *(const float4*)&xin[r][kk];
      acc[r] = fmaf(xv.x, wa, fmaf(xv.y, wb, fmaf(xv.z, wc, fmaf(xv.w, wd, acc[r]))));
    }
  }
  __syncthreads();
  #pragma unroll
  for (int r = 0; r < 8; ++r) xout[r][t] = fmaxf(acc[r], 0.f);
  __syncthreads();
  for (int r = wid; r < 8; r += 4) {
    float s = xout[r][lane] + xout[r][lane+64] + xout[r][lane+128] + xout[r][lane+192];
    s = waveSum(s);
    if (lane == 0) stats[r][0] = s * (1.f/256.f);
  }
  __syncthreads();
  for (int r = wid; r < 8; r += 4) {
    const float m = stats[r][0];
    const float d0 = xout[r][lane]-m, d1 = xout[r][lane+64]-m;
    const float d2 = xout[r][lane+128]-m, d3 = xout[r][lane+192]-m;
    const float s = waveSum(d0*d0 + d1*d1 + d2*d2 + d3*d3);
    if (lane == 0) stats[r][1] = 1.f / sqrtf(s * (1.f/256.f) + 1e-5f);
  }
  __syncthreads();
  const float w3t = w3[t], b30 = b3[0];
  #pragma unroll
  for (int r = 0; r < 8; ++r) {
    const float xn = (xout[r][t] - stats[r][0]) * stats[r][1] * G2 + B2;
    xin[r][t] = xn * w3t;
  }
  __syncthreads();
  for (int r = wid; r < 8; r += 4) {
    float s = xin[r][lane] + xin[r][lane+64] + xin[r][lane+128] + xin[r][lane+192];
    s = waveSum(s);
    if (lane == 0) roi[r0 + r] = 1.f / (1.f + expf(-(s + b30)));
  }
}

// ---------------------------------------------------------------------------
// Kernel 2: exact top-256 of 1024 per agent via bitonic sort (unchanged).
// ---------------------------------------------------------------------------
__global__ __launch_bounds__(512) void topk_kernel(
    const float* __restrict__ roi, int* __restrict__ top_idx, float* __restrict__ conf)
{
  __shared__ unsigned long long keys[1024];
  const int t = threadIdx.x;
  const int ag = blockIdx.x;
  for (int i = t; i < 1024; i += 512) {
    const unsigned int bits = __float_as_uint(roi[ag * 1024 + i]);
    keys[i] = ((unsigned long long)bits << 10) | (unsigned long long)(1023 - i);
  }
  __syncthreads();
  for (int k = 2; k <= 1024; k <<= 1) {
    for (int j = k >> 1; j > 0; j >>= 1) {
      const int i = ((t & ~(j - 1)) << 1) | (t & (j - 1));
      const int p = i | j;
      const unsigned long long a = keys[i], b = keys[p];
      const bool up = ((i & k) == 0);
      if ((a < b) == up) { keys[i] = b; keys[p] = a; }
      __syncthreads();
    }
  }
  if (t < 256) {
    const unsigned long long key = keys[t];
    const int idx = 1023 - (int)(key & 1023ull);
    const float sc = __uint_as_float((unsigned int)(key >> 10));
    top_idx[ag * 256 + t] = idx;
    conf[ag * 256 + t] = (sc > 0.7f) ? 1.0f : 0.0f;
  }
}

// ---------------------------------------------------------------------------
// Kernel 3 (fused): mfeat gather + prep (unchanged).
// ---------------------------------------------------------------------------
__global__ __launch_bounds__(256) void gather_prep_kernel(
    const float* __restrict__ bf, const int* __restrict__ top_idx,
    const float* __restrict__ conf, const float* __restrict__ ba,
    const float* __restrict__ i2j,
    float* __restrict__ mfeat, float* __restrict__ out,
    float* __restrict__ minmax, float* __restrict__ pts)
{
  const int t = threadIdx.x;
  const int blk = blockIdx.x;
  if (blk < 1536) {
    const int j = blk >> 8, idx = top_idx[blk];
    const float c = conf[blk];
    mfeat[blk * 256 + t] = bf[(j * 1024 + idx) * 256 + t] * c;
    return;
  }
  if (blk == 1536) { mfeat[ZROW + t] = 0.f; return; }
  const int id = (blk - 1537) * 256 + t;
  if (id < 49152) {
    out[id] = ba[id];
  } else if (id < 49152 + 6144) {
    const int i = id - 49152;
    const float* p = ba + i * 8;
    const float cx = p[0], cy = p[1], cz = p[2];
    const float d0 = expf(p[3]), d1 = expf(p[4]), d2 = expf(p[5]);
    const float s = fabsf(p[6]), c = fabsf(p[7]);
    const float hx = 0.5f * (d0 * c + d1 * s);
    const float hy = 0.5f * (d0 * s + d1 * c);
    const float hz = 0.5f * d2;
    float* mm = minmax + i * 6;
    mm[0] = cx - hx; mm[1] = cy - hy; mm[2] = cz - hz;
    mm[3] = cx + hx; mm[4] = cy + hy; mm[5] = cz + hz;
  } else if (id < 49152 + 6144 + 7680) {
    const int i = id - 55296;
    const int n = i / NM, jk = i % NM;
    const int jj = jk >> 8, k = jk & 255;
    const int j = jj + (jj >= n ? 1 : 0);
    const int idx = top_idx[j * 256 + k];
    const float* src = i2j + (((long)(n * 6 + j)) * 1024 + idx) * 8;
    float* dst = pts + n * 3840;
    dst[jk]        = src[0];
    dst[1280 + jk] = src[1];
    dst[2560 + jk] = src[2];
  }
}

// ---------------------------------------------------------------------------
// Kernel 5 (fused QKV -> bf16): blocks [0,127]: Q=(ego+pos)@wq+bq, scaled by
// 1/sqrt(32), stored bf16 as qb16[h][q][d]. [128,767]: K -> kb16[(b,h)][k][d].
// [768,1407]: V -> TRANSPOSED vt16[(b,h)][d][k] (thread packs its column's
// 8 k-values into one 16B store).
// ---------------------------------------------------------------------------
__global__ __launch_bounds__(256) void qkv_kernel(
    const float* __restrict__ bf, const float* __restrict__ ae,
    const float* __restrict__ wq, const float* __restrict__ bq,
    const float* __restrict__ wk, const float* __restrict__ bk,
    const float* __restrict__ wv, const float* __restrict__ bv,
    unsigned short* __restrict__ qb16, unsigned short* __restrict__ kb16,
    unsigned short* __restrict__ vt16)
{
  __shared__ float xin[8][256];
  const int t = threadIdx.x;
  const int blk = blockIdx.x;
  const float* in; const float* add = nullptr;
  const float* w; const float* bias; long r0;
  int mode;                     // 0=Q 1=K 2=V
  if (blk < 128)      { in = bf;      add = ae; w = wq; bias = bq; r0 = (long)blk * 8;        mode = 0; }
  else if (blk < 768) { in = bf + AC;           w = wk; bias = bk; r0 = (long)(blk - 128) * 8; mode = 1; }
  else                { in = bf + AC;           w = wv; bias = bv; r0 = (long)(blk - 768) * 8; mode = 2; }

  for (int r = 0; r < 8; ++r) {
    float v = in[(r0 + r) * 256 + t];
    if (add) v += add[(r0 + r) * 256 + t];
    xin[r][t] = v;
  }
  __syncthreads();
  float acc[8];
  #pragma unroll
  for (int r = 0; r < 8; ++r) acc[r] = bias[t];
  for (int kk = 0; kk < 256; kk += 4) {
    const float wa = w[(kk+0)*256+t], wb = w[(kk+1)*256+t];
    const float wc = w[(kk+2)*256+t], wd = w[(kk+3)*256+t];
    #pragma unroll
    for (int r = 0; r < 8; ++r) {
      const float4 xv = *(const float4*)&xin[r][kk];
      acc[r] = fmaf(xv.x, wa, fmaf(xv.y, wb, fmaf(xv.z, wc, fmaf(xv.w, wd, acc[r]))));
    }
  }
  const int h = t >> 5, d = t & 31;
  if (mode == 0) {
    const float SCALE = 0.17677669529663687f;   // 1/sqrt(32)
    #pragma unroll
    for (int r = 0; r < 8; ++r)
      qb16[(long)h * 32768 + (r0 + r) * 32 + d] = f2bf(acc[r] * SCALE);
  } else if (mode == 1) {
    #pragma unroll
    for (int r = 0; r < 8; ++r) {
      const long row = r0 + r;
      const int b = (int)(row >> 10), kkk = (int)(row & 1023);
      kb16[((long)(b * 8 + h)) * 32768 + kkk * 32 + d] = f2bf(acc[r]);
    }
  } else {
    const int b = (int)(r0 >> 10), kk0 = (int)(r0 & 1023);
    short8 v8;
    #pragma unroll
    for (int r = 0; r < 8; ++r) v8[r] = (short)f2bf(acc[r]);
    *(short8*)&vt16[((long)(b * 8 + h)) * 32768 + (long)d * 1024 + kk0] = v8;
  }
}

// ---------------------------------------------------------------------------
// Kernel 6: MFMA flash attention. Grid (64 qtiles, 8 heads, 5 agents), 64 thr
// (1 wave = 16 q-rows). Per 32-key step: 2 QK mfmas -> online softmax
// (shfl over 16-lane groups) -> P bf16 via LDS bounce -> 2 PV mfmas.
// Writes normalized output directly (no split/combine).
// ---------------------------------------------------------------------------
__global__ __launch_bounds__(64) void attn_kernel(
    const unsigned short* __restrict__ qb,   // [8][1024][32] pre-scaled bf16
    const unsigned short* __restrict__ kb,   // [40][1024][32] bf16
    const unsigned short* __restrict__ vt,   // [40][32][1024] bf16 (transposed)
    float* __restrict__ ob)                  // [5][1024][256]
{
  __shared__ unsigned short pls[2][16][32];
  const int l = threadIdx.x;
  const int qt = blockIdx.x, h = blockIdx.y, b = blockIdx.z;
  const int bh = b * 8 + h;
  const int r16 = l & 15, g = l >> 4;

  const short8 qf = *(const short8*)(qb + (long)h * 32768 + (qt * 16 + r16) * 32 + 8 * g);
  const unsigned short* kbase = kb + (long)bh * 32768;
  const unsigned short* vbase = vt + (long)bh * 32768;

  f32x4 oc0 = {0.f, 0.f, 0.f, 0.f};
  f32x4 oc1 = {0.f, 0.f, 0.f, 0.f};
  float m[4]    = {-1e30f, -1e30f, -1e30f, -1e30f};
  float lsum[4] = {0.f, 0.f, 0.f, 0.f};

  short8 kf0 = *(const short8*)(kbase + (r16) * 32 + 8 * g);
  short8 kf1 = *(const short8*)(kbase + (16 + r16) * 32 + 8 * g);
  short8 vf0 = *(const short8*)(vbase + (long)r16 * 1024 + 8 * g);
  short8 vf1 = *(const short8*)(vbase + (long)(16 + r16) * 1024 + 8 * g);

  #pragma unroll 1
  for (int K0 = 0; K0 < 1024; K0 += 32) {
    const int Kn = (K0 + 32 < 1024) ? K0 + 32 : 0;   // prefetch (clamped; last unused)
    const short8 nk0 = *(const short8*)(kbase + (Kn + r16) * 32 + 8 * g);
    const short8 nk1 = *(const short8*)(kbase + (Kn + 16 + r16) * 32 + 8 * g);
    const short8 nv0 = *(const short8*)(vbase + (long)r16 * 1024 + Kn + 8 * g);
    const short8 nv1 = *(const short8*)(vbase + (long)(16 + r16) * 1024 + Kn + 8 * g);

    const f32x4 z = {0.f, 0.f, 0.f, 0.f};
    f32x4 s0 = __builtin_amdgcn_mfma_f32_16x16x32_bf16(qf, kf0, z, 0, 0, 0);
    f32x4 s1 = __builtin_amdgcn_mfma_f32_16x16x32_bf16(qf, kf1, z, 0, 0, 0);

    const int buf = (K0 >> 5) & 1;
    #pragma unroll
    for (int r = 0; r < 4; ++r) {
      float mx = fmaxf(s0[r], s1[r]);
      mx = fmaxf(mx, __shfl_xor(mx, 1));
      mx = fmaxf(mx, __shfl_xor(mx, 2));
      mx = fmaxf(mx, __shfl_xor(mx, 4));
      mx = fmaxf(mx, __shfl_xor(mx, 8));
      const float nm = fmaxf(m[r], mx);
      const float sc = __expf(m[r] - nm);
      m[r] = nm;
      const float p0 = __expf(s0[r] - nm);
      const float p1 = __expf(s1[r] - nm);
      float rs = p0 + p1;
      rs += __shfl_xor(rs, 1);
      rs += __shfl_xor(rs, 2);
      rs += __shfl_xor(rs, 4);
      rs += __shfl_xor(rs, 8);
      lsum[r] = lsum[r] * sc + rs;
      oc0[r] *= sc; oc1[r] *= sc;
      pls[buf][4 * g + r][r16]      = f2bf(p0);
      pls[buf][4 * g + r][16 + r16] = f2bf(p1);
    }
    __syncthreads();
    const short8 pf = *(const short8*)&pls[buf][r16][8 * g];
    oc0 = __builtin_amdgcn_mfma_f32_16x16x32_bf16(pf, vf0, oc0, 0, 0, 0);
    oc1 = __builtin_amdgcn_mfma_f32_16x16x32_bf16(pf, vf1, oc1, 0, 0, 0);
    kf0 = nk0; kf1 = nk1; vf0 = nv0; vf1 = nv1;
  }

  float* dst = ob + ((long)(b * 1024 + qt * 16)) * 256 + h * 32;
  #pragma unroll
  for (int r = 0; r < 4; ++r) {
    const float inv = 1.f / lsum[r];
    const int row = 4 * g + r;
    dst[row * 256 + r16]      = oc0[r] * inv;
    dst[row * 256 + 16 + r16] = oc1[r] * inv;
  }
}

// ---------------------------------------------------------------------------
// Kernel 7: res = 5*ego + (sum_b o_b) @ wo + 5*bo   (unchanged)
// ---------------------------------------------------------------------------
__global__ __launch_bounds__(256) void res_kernel(
    const float* __restrict__ obuf, const float* __restrict__ bf,
    const float* __restrict__ wo, const float* __restrict__ bo,
    float* __restrict__ res)
{
  __shared__ float xin[4][256];
  const int t = threadIdx.x;
  const int r0 = blockIdx.x * 4;
  for (int r = 0; r < 4; ++r) {
    const long a = r0 + r;
    float v = 0.f;
    #pragma unroll
    for (int b = 0; b < 5; ++b) v += obuf[(b * 1024 + a) * 256 + t];
    xin[r][t] = v;
  }
  __syncthreads();
  float acc[4];
  #pragma unroll
  for (int r = 0; r < 4; ++r) acc[r] = 0.f;
  for (int kk = 0; kk < 256; kk += 4) {
    const float wa = wo[(kk+0)*256+t], wb = wo[(kk+1)*256+t];
    const float wc = wo[(kk+2)*256+t], wd = wo[(kk+3)*256+t];
    #pragma unroll
    for (int r = 0; r < 4; ++r) {
      const float4 xv = *(const float4*)&xin[r][kk];
      acc[r] = fmaf(xv.x, wa, fmaf(xv.y, wb, fmaf(xv.z, wc, fmaf(xv.w, wd, acc[r]))));
    }
  }
  const float bot = 5.f * bo[t];
  for (int r = 0; r < 4; ++r)
    res[(r0 + r) * 256 + t] = acc[r] + bot + 5.f * bf[(r0 + r) * 256 + t];
}

// ---------------------------------------------------------------------------
// Kernel 8: sparse box aggregation + final output (unchanged).
// ---------------------------------------------------------------------------
__global__ __launch_bounds__(256) void agg_kernel(
    const float* __restrict__ pts, const float* __restrict__ minmax,
    const float* __restrict__ conf, const float* __restrict__ mfeat,
    const float* __restrict__ res, float* __restrict__ outf)
{
  __shared__ int list[NM];
  __shared__ int wcnt[4];
  __shared__ int wicnt[4];
  const int t = threadIdx.x, w = t >> 6, lane = t & 63;
  const int n = blockIdx.x >> 10;
  const int a = blockIdx.x & 1023;

  const float* mm = minmax + (n * 1024 + a) * 6;
  const float mnx = mm[0], mny = mm[1], mnz = mm[2];
  const float mxx = mm[3], mxy = mm[4], mxz = mm[5];

  const float* P = pts + n * 3840;
  int localBase = 0, insideCnt = 0;
  #pragma unroll
  for (int s = 0; s < 5; ++s) {
    const int mpt = w * 320 + s * 64 + lane;
    const float x = P[mpt], y = P[1280 + mpt], z = P[2560 + mpt];
    const bool in = (x >= mnx) & (x <= mxx) & (y >= mny) & (y <= mxy) &
                    (z >= mnz) & (z <= mxz);
    const int jj = mpt >> 8;
    const int j = jj + (jj >= n ? 1 : 0);
    const int row = (j << 8) | (mpt & 255);
    const bool keep = in && (conf[row] > 0.f);
    const unsigned long long kmask = __ballot(keep);
    if (keep)
      list[w * 320 + localBase + __popcll(kmask & ((1ull << lane) - 1ull))] = row << 8;
    localBase += __popcll(kmask);
    insideCnt += __popcll(__ballot(in));
  }
  const int nwp = (localBase + 3) & ~3;
  if (lane < nwp - localBase) list[w * 320 + localBase + lane] = ZROW;
  if (lane == 0) { wcnt[w] = nwp; wicnt[w] = insideCnt; }
  __syncthreads();

  const int cnt = wicnt[0] + wicnt[1] + wicnt[2] + wicnt[3];
  float a0 = 0.f, a1 = 0.f, a2 = 0.f, a3 = 0.f;
  const float* mf = mfeat + t;
  #pragma unroll 1
  for (int ww = 0; ww < 4; ++ww) {
    const int base = ww * 320, nw = wcnt[ww];
    #pragma unroll 1
    for (int l = 0; l < nw; l += 4) {
      const int o0 = list[base + l],     o1 = list[base + l + 1];
      const int o2 = list[base + l + 2], o3 = list[base + l + 3];
      a0 += mf[o0]; a1 += mf[o1];
      a2 += mf[o2]; a3 += mf[o3];
    }
  }
  const float acc = (a0 + a1) + (a2 + a3);
  outf[((long)(n * 1024 + a)) * 256 + t] =
      res[a * 256 + t] + acc / (float)(cnt > 0 ? cnt : 1);
}

// ---------------------------------------------------------------------------
extern "C" void kernel_launch(void* const* d_in, const int* in_sizes, int n_in,
                              void* d_out, int out_size, void* d_ws, size_t ws_size,
                              hipStream_t stream)
{
  (void)in_sizes; (void)n_in; (void)out_size; (void)ws_size;
  const float* i2j_anchor  = (const float*)d_in[0];
  const float* b_anchor    = (const float*)d_in[1];
  const float* b_feature   = (const float*)d_in[2];
  const float* anchor_embed= (const float*)d_in[5];
  const float* cls_w1 = (const float*)d_in[6];
  const float* cls_b1 = (const float*)d_in[7];
  const float* cls_g1 = (const float*)d_in[8];
  const float* cls_bb1= (const float*)d_in[9];
  const float* cls_w2 = (const float*)d_in[10];
  const float* cls_b2 = (const float*)d_in[11];
  const float* cls_g2 = (const float*)d_in[12];
  const float* cls_bb2= (const float*)d_in[13];
  const float* cls_w3 = (const float*)d_in[14];
  const float* cls_b3 = (const float*)d_in[15];
  const float* wq = (const float*)d_in[26];
  const float* bq = (const float*)d_in[27];
  const float* wk = (const float*)d_in[28];
  const float* bk = (const float*)d_in[29];
  const float* wv = (const float*)d_in[30];
  const float* bv = (const float*)d_in[31];
  const float* wo = (const float*)d_in[32];
  const float* bo = (const float*)d_in[33];
  float* out = (float*)d_out;

  // workspace layout (float offsets)
  float* ws = (float*)d_ws;
  float* roi    = ws;                  // 6144
  int*   tidx   = (int*)(ws + 6144);   // 1536
  float* conf   = ws + 7680;           // 1536
  float* mfeat  = ws + 9216;           // 393472 (incl. zero row)
  float* obuf   = ws + 402688;         // 1310720
  float* resbuf = ws + 1713408;        // 262144
  float* minmax = ws + 1975552;        // 36864
  float* pts    = ws + 2012416;        // 23040 -> 2035456
  unsigned short* qb16 = (unsigned short*)(ws + 2035456);  // 262144 bf16 (131072 f)
  unsigned short* kb16 = (unsigned short*)(ws + 2166528);  // 1310720 bf16 (655360 f)
  unsigned short* vt16 = (unsigned short*)(ws + 2821888);  // 1310720 bf16 (655360 f)
  // end: 3477248 floats = 13.9 MB (ws_size measured >= 64 MB in prior rounds)

  cls_kernel<<<768, 256, 0, stream>>>(b_feature, cls_w1, cls_b1, cls_g1, cls_bb1,
                                      cls_w2, cls_b2, cls_g2, cls_bb2,
                                      cls_w3, cls_b3, roi);
  topk_kernel<<<6, 512, 0, stream>>>(roi, tidx, conf);
  gather_prep_kernel<<<1783, 256, 0, stream>>>(b_feature, tidx, conf, b_anchor,
                                               i2j_anchor, mfeat, out, minmax, pts);
  qkv_kernel<<<1408, 256, 0, stream>>>(b_feature, anchor_embed,
                                       wq, bq, wk, bk, wv, bv, qb16, kb16, vt16);
  attn_kernel<<<dim3(64, 8, 5), 64, 0, stream>>>(qb16, kb16, vt16, obuf);
  res_kernel<<<256, 256, 0, stream>>>(obuf, b_feature, wo, bo, resbuf);
  agg_kernel<<<6144, 256, 0, stream>>>(pts, minmax, conf, mfeat, resbuf, out + 49152);
}

// Round 13
// 316.999 us; speedup vs baseline: 1.4725x; 1.0611x over previous
//
#include <hip/hip_runtime.h>

// PointEncoderV6 — MI355X implementation. Round 13.
// R13 change (single variable): agg gather ILP 4->8 accumulators + unroll-2
// (x8 list padding). R12 counters: agg 65us, occ 34%, VALU 33%, HBM 2.3%
// => latency-chain bound (4 loads in flight, ~370 stall-cyc per 4 rows).
// R12's MFMA attention kept (attn now < 64us, combine removed).

#define N_AG   6
#define N_ANCH 1024
#define C_FEAT 256
#define D_ANCH 8
#define KTOP   256
#define NM     1280          // (N-1)*K points per agent
#define ZROW   393216        // element offset of the zero row in mfeat (row 1536)
#define AC     262144        // N_ANCH * C_FEAT

using short8 = __attribute__((ext_vector_type(8))) short;
using f32x4  = __attribute__((ext_vector_type(4))) float;

__device__ __forceinline__ float waveSum(float v) {
  #pragma unroll
  for (int off = 32; off; off >>= 1) v += __shfl_down(v, off);
  return v;
}

__device__ __forceinline__ unsigned short f2bf(float x) {   // round-to-nearest-even
  const unsigned int b = __float_as_uint(x);
  return (unsigned short)((b + 0x7FFFu + ((b >> 16) & 1u)) >> 16);
}

// ---------------------------------------------------------------------------
// Kernel 1: fused cls MLP (unchanged)
// ---------------------------------------------------------------------------
__global__ __launch_bounds__(256) void cls_kernel(
    const float* __restrict__ bf,
    const float* __restrict__ w1, const float* __restrict__ b1,
    const float* __restrict__ g1, const float* __restrict__ bb1,
    const float* __restrict__ w2, const float* __restrict__ b2,
    const float* __restrict__ g2, const float* __restrict__ bb2,
    const float* __restrict__ w3, const float* __restrict__ b3,
    float* __restrict__ roi)
{
  __shared__ float xin[8][256];
  __shared__ float xout[8][256];
  __shared__ float stats[8][2];
  const int t = threadIdx.x;
  const int wid = t >> 6, lane = t & 63;
  const int r0 = blockIdx.x * 8;

  for (int r = 0; r < 8; ++r) xin[r][t] = bf[(r0 + r) * 256 + t];

  const float G1 = g1[t], B1 = bb1[t], G2 = g2[t], B2 = bb2[t];
  float acc[8];

  #pragma unroll
  for (int r = 0; r < 8; ++r) acc[r] = b1[t];
  __syncthreads();
  for (int kk = 0; kk < 256; kk += 4) {
    const float wa = w1[(kk+0)*256+t], wb = w1[(kk+1)*256+t];
    const float wc = w1[(kk+2)*256+t], wd = w1[(kk+3)*256+t];
    #pragma unroll
    for (int r = 0; r < 8; ++r) {
      const float4 xv = *(const float4*)&xin[r][kk];
      acc[r] = fmaf(xv.x, wa, fmaf(xv.y, wb, fmaf(xv.z, wc, fmaf(xv.w, wd, acc[r]))));
    }
  }
  #pragma unroll
  for (int r = 0; r < 8; ++r) xout[r][t] = fmaxf(acc[r], 0.f);
  __syncthreads();
  for (int r = wid; r < 8; r += 4) {
    float s = xout[r][lane] + xout[r][lane+64] + xout[r][lane+128] + xout[r][lane+192];
    s = waveSum(s);
    if (lane == 0) stats[r][0] = s * (1.f/256.f);
  }
  __syncthreads();
  for (int r = wid; r < 8; r += 4) {
    const float m = stats[r][0];
    const float d0 = xout[r][lane]-m, d1 = xout[r][lane+64]-m;
    const float d2 = xout[r][lane+128]-m, d3 = xout[r][lane+192]-m;
    const float s = waveSum(d0*d0 + d1*d1 + d2*d2 + d3*d3);
    if (lane == 0) stats[r][1] = 1.f / sqrtf(s * (1.f/256.f) + 1e-5f);
  }
  __syncthreads();
  #pragma unroll
  for (int r = 0; r < 8; ++r)
    xin[r][t] = (xout[r][t] - stats[r][0]) * stats[r][1] * G1 + B1;
  __syncthreads();

  #pragma unroll
  for (int r = 0; r < 8; ++r) acc[r] = b2[t];
  for (int kk = 0; kk < 256; kk += 4) {
    const float wa = w2[(kk+0)*256+t], wb = w2[(kk+1)*256+t];
    const float wc = w2[(kk+2)*256+t], wd = w2[(kk+3)*256+t];
    #pragma unroll
    for (int r = 0; r < 8; ++r) {
      const float4 xv = *(const float4*)&xin[r][kk];
      acc[r] = fmaf(xv.x, wa, fmaf(xv.y, wb, fmaf(xv.z, wc, fmaf(xv.w, wd, acc[r]))));
    }
  }
  __syncthreads();
  #pragma unroll
  for (int r = 0; r < 8; ++r) xout[r][t] = fmaxf(acc[r], 0.f);
  __syncthreads();
  for (int r = wid; r < 8; r += 4) {
    float s = xout[r][lane] + xout[r][lane+64] + xout[r][lane+128] + xout[r][lane+192];
    s = waveSum(s);
    if (lane == 0) stats[r][0] = s * (1.f/256.f);
  }
  __syncthreads();
  for (int r = wid; r < 8; r += 4) {
    const float m = stats[r][0];
    const float d0 = xout[r][lane]-m, d1 = xout[r][lane+64]-m;
    const float d2 = xout[r][lane+128]-m, d3 = xout[r][lane+192]-m;
    const float s = waveSum(d0*d0 + d1*d1 + d2*d2 + d3*d3);
    if (lane == 0) stats[r][1] = 1.f / sqrtf(s * (1.f/256.f) + 1e-5f);
  }
  __syncthreads();
  const float w3t = w3[t], b30 = b3[0];
  #pragma unroll
  for (int r = 0; r < 8; ++r) {
    const float xn = (xout[r][t] - stats[r][0]) * stats[r][1] * G2 + B2;
    xin[r][t] = xn * w3t;
  }
  __syncthreads();
  for (int r = wid; r < 8; r += 4) {
    float s = xin[r][lane] + xin[r][lane+64] + xin[r][lane+128] + xin[r][lane+192];
    s = waveSum(s);
    if (lane == 0) roi[r0 + r] = 1.f / (1.f + expf(-(s + b30)));
  }
}

// ---------------------------------------------------------------------------
// Kernel 2: exact top-256 of 1024 per agent via bitonic sort (unchanged).
// ---------------------------------------------------------------------------
__global__ __launch_bounds__(512) void topk_kernel(
    const float* __restrict__ roi, int* __restrict__ top_idx, float* __restrict__ conf)
{
  __shared__ unsigned long long keys[1024];
  const int t = threadIdx.x;
  const int ag = blockIdx.x;
  for (int i = t; i < 1024; i += 512) {
    const unsigned int bits = __float_as_uint(roi[ag * 1024 + i]);
    keys[i] = ((unsigned long long)bits << 10) | (unsigned long long)(1023 - i);
  }
  __syncthreads();
  for (int k = 2; k <= 1024; k <<= 1) {
    for (int j = k >> 1; j > 0; j >>= 1) {
      const int i = ((t & ~(j - 1)) << 1) | (t & (j - 1));
      const int p = i | j;
      const unsigned long long a = keys[i], b = keys[p];
      const bool up = ((i & k) == 0);
      if ((a < b) == up) { keys[i] = b; keys[p] = a; }
      __syncthreads();
    }
  }
  if (t < 256) {
    const unsigned long long key = keys[t];
    const int idx = 1023 - (int)(key & 1023ull);
    const float sc = __uint_as_float((unsigned int)(key >> 10));
    top_idx[ag * 256 + t] = idx;
    conf[ag * 256 + t] = (sc > 0.7f) ? 1.0f : 0.0f;
  }
}

// ---------------------------------------------------------------------------
// Kernel 3 (fused): mfeat gather + prep (unchanged).
// ---------------------------------------------------------------------------
__global__ __launch_bounds__(256) void gather_prep_kernel(
    const float* __restrict__ bf, const int* __restrict__ top_idx,
    const float* __restrict__ conf, const float* __restrict__ ba,
    const float* __restrict__ i2j,
    float* __restrict__ mfeat, float* __restrict__ out,
    float* __restrict__ minmax, float* __restrict__ pts)
{
  const int t = threadIdx.x;
  const int blk = blockIdx.x;
  if (blk < 1536) {
    const int j = blk >> 8, idx = top_idx[blk];
    const float c = conf[blk];
    mfeat[blk * 256 + t] = bf[(j * 1024 + idx) * 256 + t] * c;
    return;
  }
  if (blk == 1536) { mfeat[ZROW + t] = 0.f; return; }
  const int id = (blk - 1537) * 256 + t;
  if (id < 49152) {
    out[id] = ba[id];
  } else if (id < 49152 + 6144) {
    const int i = id - 49152;
    const float* p = ba + i * 8;
    const float cx = p[0], cy = p[1], cz = p[2];
    const float d0 = expf(p[3]), d1 = expf(p[4]), d2 = expf(p[5]);
    const float s = fabsf(p[6]), c = fabsf(p[7]);
    const float hx = 0.5f * (d0 * c + d1 * s);
    const float hy = 0.5f * (d0 * s + d1 * c);
    const float hz = 0.5f * d2;
    float* mm = minmax + i * 6;
    mm[0] = cx - hx; mm[1] = cy - hy; mm[2] = cz - hz;
    mm[3] = cx + hx; mm[4] = cy + hy; mm[5] = cz + hz;
  } else if (id < 49152 + 6144 + 7680) {
    const int i = id - 55296;
    const int n = i / NM, jk = i % NM;
    const int jj = jk >> 8, k = jk & 255;
    const int j = jj + (jj >= n ? 1 : 0);
    const int idx = top_idx[j * 256 + k];
    const float* src = i2j + (((long)(n * 6 + j)) * 1024 + idx) * 8;
    float* dst = pts + n * 3840;
    dst[jk]        = src[0];
    dst[1280 + jk] = src[1];
    dst[2560 + jk] = src[2];
  }
}

// ---------------------------------------------------------------------------
// Kernel 5 (fused QKV -> bf16): unchanged from R12.
// ---------------------------------------------------------------------------
__global__ __launch_bounds__(256) void qkv_kernel(
    const float* __restrict__ bf, const float* __restrict__ ae,
    const float* __restrict__ wq, const float* __restrict__ bq,
    const float* __restrict__ wk, const float* __restrict__ bk,
    const float* __restrict__ wv, const float* __restrict__ bv,
    unsigned short* __restrict__ qb16, unsigned short* __restrict__ kb16,
    unsigned short* __restrict__ vt16)
{
  __shared__ float xin[8][256];
  const int t = threadIdx.x;
  const int blk = blockIdx.x;
  const float* in; const float* add = nullptr;
  const float* w; const float* bias; long r0;
  int mode;                     // 0=Q 1=K 2=V
  if (blk < 128)      { in = bf;      add = ae; w = wq; bias = bq; r0 = (long)blk * 8;        mode = 0; }
  else if (blk < 768) { in = bf + AC;           w = wk; bias = bk; r0 = (long)(blk - 128) * 8; mode = 1; }
  else                { in = bf + AC;           w = wv; bias = bv; r0 = (long)(blk - 768) * 8; mode = 2; }

  for (int r = 0; r < 8; ++r) {
    float v = in[(r0 + r) * 256 + t];
    if (add) v += add[(r0 + r) * 256 + t];
    xin[r][t] = v;
  }
  __syncthreads();
  float acc[8];
  #pragma unroll
  for (int r = 0; r < 8; ++r) acc[r] = bias[t];
  for (int kk = 0; kk < 256; kk += 4) {
    const float wa = w[(kk+0)*256+t], wb = w[(kk+1)*256+t];
    const float wc = w[(kk+2)*256+t], wd = w[(kk+3)*256+t];
    #pragma unroll
    for (int r = 0; r < 8; ++r) {
      const float4 xv = *(const float4*)&xin[r][kk];
      acc[r] = fmaf(xv.x, wa, fmaf(xv.y, wb, fmaf(xv.z, wc, fmaf(xv.w, wd, acc[r]))));
    }
  }
  const int h = t >> 5, d = t & 31;
  if (mode == 0) {
    const float SCALE = 0.17677669529663687f;   // 1/sqrt(32)
    #pragma unroll
    for (int r = 0; r < 8; ++r)
      qb16[(long)h * 32768 + (r0 + r) * 32 + d] = f2bf(acc[r] * SCALE);
  } else if (mode == 1) {
    #pragma unroll
    for (int r = 0; r < 8; ++r) {
      const long row = r0 + r;
      const int b = (int)(row >> 10), kkk = (int)(row & 1023);
      kb16[((long)(b * 8 + h)) * 32768 + kkk * 32 + d] = f2bf(acc[r]);
    }
  } else {
    const int b = (int)(r0 >> 10), kk0 = (int)(r0 & 1023);
    short8 v8;
    #pragma unroll
    for (int r = 0; r < 8; ++r) v8[r] = (short)f2bf(acc[r]);
    *(short8*)&vt16[((long)(b * 8 + h)) * 32768 + (long)d * 1024 + kk0] = v8;
  }
}

// ---------------------------------------------------------------------------
// Kernel 6: MFMA flash attention (unchanged from R12).
// ---------------------------------------------------------------------------
__global__ __launch_bounds__(64) void attn_kernel(
    const unsigned short* __restrict__ qb,   // [8][1024][32] pre-scaled bf16
    const unsigned short* __restrict__ kb,   // [40][1024][32] bf16
    const unsigned short* __restrict__ vt,   // [40][32][1024] bf16 (transposed)
    float* __restrict__ ob)                  // [5][1024][256]
{
  __shared__ unsigned short pls[2][16][32];
  const int l = threadIdx.x;
  const int qt = blockIdx.x, h = blockIdx.y, b = blockIdx.z;
  const int bh = b * 8 + h;
  const int r16 = l & 15, g = l >> 4;

  const short8 qf = *(const short8*)(qb + (long)h * 32768 + (qt * 16 + r16) * 32 + 8 * g);
  const unsigned short* kbase = kb + (long)bh * 32768;
  const unsigned short* vbase = vt + (long)bh * 32768;

  f32x4 oc0 = {0.f, 0.f, 0.f, 0.f};
  f32x4 oc1 = {0.f, 0.f, 0.f, 0.f};
  float m[4]    = {-1e30f, -1e30f, -1e30f, -1e30f};
  float lsum[4] = {0.f, 0.f, 0.f, 0.f};

  short8 kf0 = *(const short8*)(kbase + (r16) * 32 + 8 * g);
  short8 kf1 = *(const short8*)(kbase + (16 + r16) * 32 + 8 * g);
  short8 vf0 = *(const short8*)(vbase + (long)r16 * 1024 + 8 * g);
  short8 vf1 = *(const short8*)(vbase + (long)(16 + r16) * 1024 + 8 * g);

  #pragma unroll 1
  for (int K0 = 0; K0 < 1024; K0 += 32) {
    const int Kn = (K0 + 32 < 1024) ? K0 + 32 : 0;   // prefetch (clamped; last unused)
    const short8 nk0 = *(const short8*)(kbase + (Kn + r16) * 32 + 8 * g);
    const short8 nk1 = *(const short8*)(kbase + (Kn + 16 + r16) * 32 + 8 * g);
    const short8 nv0 = *(const short8*)(vbase + (long)r16 * 1024 + Kn + 8 * g);
    const short8 nv1 = *(const short8*)(vbase + (long)(16 + r16) * 1024 + Kn + 8 * g);

    const f32x4 z = {0.f, 0.f, 0.f, 0.f};
    f32x4 s0 = __builtin_amdgcn_mfma_f32_16x16x32_bf16(qf, kf0, z, 0, 0, 0);
    f32x4 s1 = __builtin_amdgcn_mfma_f32_16x16x32_bf16(qf, kf1, z, 0, 0, 0);

    const int buf = (K0 >> 5) & 1;
    #pragma unroll
    for (int r = 0; r < 4; ++r) {
      float mx = fmaxf(s0[r], s1[r]);
      mx = fmaxf(mx, __shfl_xor(mx, 1));
      mx = fmaxf(mx, __shfl_xor(mx, 2));
      mx = fmaxf(mx, __shfl_xor(mx, 4));
      mx = fmaxf(mx, __shfl_xor(mx, 8));
      const float nm = fmaxf(m[r], mx);
      const float sc = __expf(m[r] - nm);
      m[r] = nm;
      const float p0 = __expf(s0[r] - nm);
      const float p1 = __expf(s1[r] - nm);
      float rs = p0 + p1;
      rs += __shfl_xor(rs, 1);
      rs += __shfl_xor(rs, 2);
      rs += __shfl_xor(rs, 4);
      rs += __shfl_xor(rs, 8);
      lsum[r] = lsum[r] * sc + rs;
      oc0[r] *= sc; oc1[r] *= sc;
      pls[buf][4 * g + r][r16]      = f2bf(p0);
      pls[buf][4 * g + r][16 + r16] = f2bf(p1);
    }
    __syncthreads();
    const short8 pf = *(const short8*)&pls[buf][r16][8 * g];
    oc0 = __builtin_amdgcn_mfma_f32_16x16x32_bf16(pf, vf0, oc0, 0, 0, 0);
    oc1 = __builtin_amdgcn_mfma_f32_16x16x32_bf16(pf, vf1, oc1, 0, 0, 0);
    kf0 = nk0; kf1 = nk1; vf0 = nv0; vf1 = nv1;
  }

  float* dst = ob + ((long)(b * 1024 + qt * 16)) * 256 + h * 32;
  #pragma unroll
  for (int r = 0; r < 4; ++r) {
    const float inv = 1.f / lsum[r];
    const int row = 4 * g + r;
    dst[row * 256 + r16]      = oc0[r] * inv;
    dst[row * 256 + 16 + r16] = oc1[r] * inv;
  }
}

// ---------------------------------------------------------------------------
// Kernel 7: res = 5*ego + (sum_b o_b) @ wo + 5*bo   (unchanged)
// ---------------------------------------------------------------------------
__global__ __launch_bounds__(256) void res_kernel(
    const float* __restrict__ obuf, const float* __restrict__ bf,
    const float* __restrict__ wo, const float* __restrict__ bo,
    float* __restrict__ res)
{
  __shared__ float xin[4][256];
  const int t = threadIdx.x;
  const int r0 = blockIdx.x * 4;
  for (int r = 0; r < 4; ++r) {
    const long a = r0 + r;
    float v = 0.f;
    #pragma unroll
    for (int b = 0; b < 5; ++b) v += obuf[(b * 1024 + a) * 256 + t];
    xin[r][t] = v;
  }
  __syncthreads();
  float acc[4];
  #pragma unroll
  for (int r = 0; r < 4; ++r) acc[r] = 0.f;
  for (int kk = 0; kk < 256; kk += 4) {
    const float wa = wo[(kk+0)*256+t], wb = wo[(kk+1)*256+t];
    const float wc = wo[(kk+2)*256+t], wd = wo[(kk+3)*256+t];
    #pragma unroll
    for (int r = 0; r < 4; ++r) {
      const float4 xv = *(const float4*)&xin[r][kk];
      acc[r] = fmaf(xv.x, wa, fmaf(xv.y, wb, fmaf(xv.z, wc, fmaf(xv.w, wd, acc[r]))));
    }
  }
  const float bot = 5.f * bo[t];
  for (int r = 0; r < 4; ++r)
    res[(r0 + r) * 256 + t] = acc[r] + bot + 5.f * bf[(r0 + r) * 256 + t];
}

// ---------------------------------------------------------------------------
// Kernel 8: sparse box aggregation + final output. ONE anchor per block,
// grid 6144. Per-wave private compaction; conf-filtered list (x8 padded);
// R13: ILP-8 gather with unroll-2 (up to 16 loads in flight).
// ---------------------------------------------------------------------------
__global__ __launch_bounds__(256) void agg_kernel(
    const float* __restrict__ pts, const float* __restrict__ minmax,
    const float* __restrict__ conf, const float* __restrict__ mfeat,
    const float* __restrict__ res, float* __restrict__ outf)
{
  __shared__ int list[NM];
  __shared__ int wcnt[4];      // padded list length per wave
  __shared__ int wicnt[4];     // inside count per wave
  const int t = threadIdx.x, w = t >> 6, lane = t & 63;
  const int n = blockIdx.x >> 10;
  const int a = blockIdx.x & 1023;

  const float* mm = minmax + (n * 1024 + a) * 6;
  const float mnx = mm[0], mny = mm[1], mnz = mm[2];
  const float mxx = mm[3], mxy = mm[4], mxz = mm[5];

  const float* P = pts + n * 3840;
  int localBase = 0, insideCnt = 0;
  #pragma unroll
  for (int s = 0; s < 5; ++s) {
    const int mpt = w * 320 + s * 64 + lane;
    const float x = P[mpt], y = P[1280 + mpt], z = P[2560 + mpt];
    const bool in = (x >= mnx) & (x <= mxx) & (y >= mny) & (y <= mxy) &
                    (z >= mnz) & (z <= mxz);
    const int jj = mpt >> 8;
    const int j = jj + (jj >= n ? 1 : 0);
    const int row = (j << 8) | (mpt & 255);
    const bool keep = in && (conf[row] > 0.f);
    const unsigned long long kmask = __ballot(keep);
    if (keep)
      list[w * 320 + localBase + __popcll(kmask & ((1ull << lane) - 1ull))] = row << 8;
    localBase += __popcll(kmask);
    insideCnt += __popcll(__ballot(in));
  }
  const int nwp = (localBase + 7) & ~7;          // x8 pad (section=320, 320%8==0: safe)
  if (lane < nwp - localBase) list[w * 320 + localBase + lane] = ZROW;
  if (lane == 0) { wcnt[w] = nwp; wicnt[w] = insideCnt; }
  __syncthreads();

  const int cnt = wicnt[0] + wicnt[1] + wicnt[2] + wicnt[3];
  float a0 = 0.f, a1 = 0.f, a2 = 0.f, a3 = 0.f;
  float a4 = 0.f, a5 = 0.f, a6 = 0.f, a7 = 0.f;
  const float* mf = mfeat + t;
  #pragma unroll 1
  for (int ww = 0; ww < 4; ++ww) {
    const int base = ww * 320, nw = wcnt[ww];
    #pragma unroll 2
    for (int l = 0; l < nw; l += 8) {
      const int o0 = list[base + l],     o1 = list[base + l + 1];
      const int o2 = list[base + l + 2], o3 = list[base + l + 3];
      const int o4 = list[base + l + 4], o5 = list[base + l + 5];
      const int o6 = list[base + l + 6], o7 = list[base + l + 7];
      a0 += mf[o0]; a1 += mf[o1]; a2 += mf[o2]; a3 += mf[o3];
      a4 += mf[o4]; a5 += mf[o5]; a6 += mf[o6]; a7 += mf[o7];
    }
  }
  const float acc = ((a0 + a1) + (a2 + a3)) + ((a4 + a5) + (a6 + a7));
  outf[((long)(n * 1024 + a)) * 256 + t] =
      res[a * 256 + t] + acc / (float)(cnt > 0 ? cnt : 1);
}

// ---------------------------------------------------------------------------
extern "C" void kernel_launch(void* const* d_in, const int* in_sizes, int n_in,
                              void* d_out, int out_size, void* d_ws, size_t ws_size,
                              hipStream_t stream)
{
  (void)in_sizes; (void)n_in; (void)out_size; (void)ws_size;
  const float* i2j_anchor  = (const float*)d_in[0];
  const float* b_anchor    = (const float*)d_in[1];
  const float* b_feature   = (const float*)d_in[2];
  const float* anchor_embed= (const float*)d_in[5];
  const float* cls_w1 = (const float*)d_in[6];
  const float* cls_b1 = (const float*)d_in[7];
  const float* cls_g1 = (const float*)d_in[8];
  const float* cls_bb1= (const float*)d_in[9];
  const float* cls_w2 = (const float*)d_in[10];
  const float* cls_b2 = (const float*)d_in[11];
  const float* cls_g2 = (const float*)d_in[12];
  const float* cls_bb2= (const float*)d_in[13];
  const float* cls_w3 = (const float*)d_in[14];
  const float* cls_b3 = (const float*)d_in[15];
  const float* wq = (const float*)d_in[26];
  const float* bq = (const float*)d_in[27];
  const float* wk = (const float*)d_in[28];
  const float* bk = (const float*)d_in[29];
  const float* wv = (const float*)d_in[30];
  const float* bv = (const float*)d_in[31];
  const float* wo = (const float*)d_in[32];
  const float* bo = (const float*)d_in[33];
  float* out = (float*)d_out;

  // workspace layout (float offsets)
  float* ws = (float*)d_ws;
  float* roi    = ws;                  // 6144
  int*   tidx   = (int*)(ws + 6144);   // 1536
  float* conf   = ws + 7680;           // 1536
  float* mfeat  = ws + 9216;           // 393472 (incl. zero row)
  float* obuf   = ws + 402688;         // 1310720
  float* resbuf = ws + 1713408;        // 262144
  float* minmax = ws + 1975552;        // 36864
  float* pts    = ws + 2012416;        // 23040 -> 2035456
  unsigned short* qb16 = (unsigned short*)(ws + 2035456);  // 262144 bf16
  unsigned short* kb16 = (unsigned short*)(ws + 2166528);  // 1310720 bf16
  unsigned short* vt16 = (unsigned short*)(ws + 2821888);  // 1310720 bf16
  // end: 3477248 floats = 13.9 MB

  cls_kernel<<<768, 256, 0, stream>>>(b_feature, cls_w1, cls_b1, cls_g1, cls_bb1,
                                      cls_w2, cls_b2, cls_g2, cls_bb2,
                                      cls_w3, cls_b3, roi);
  topk_kernel<<<6, 512, 0, stream>>>(roi, tidx, conf);
  gather_prep_kernel<<<1783, 256, 0, stream>>>(b_feature, tidx, conf, b_anchor,
                                               i2j_anchor, mfeat, out, minmax, pts);
  qkv_kernel<<<1408, 256, 0, stream>>>(b_feature, anchor_embed,
                                       wq, bq, wk, bk, wv, bv, qb16, kb16, vt16);
  attn_kernel<<<dim3(64, 8, 5), 64, 0, stream>>>(qb16, kb16, vt16, obuf);
  res_kernel<<<256, 256, 0, stream>>>(obuf, b_feature, wo, bo, resbuf);
  agg_kernel<<<6144, 256, 0, stream>>>(pts, minmax, conf, mfeat, resbuf, out + 49152);
}